// Round 9
// baseline (178.952 us; speedup 1.0000x reference)
//
#include <hip/hip_runtime.h>
#include <stdint.h>

typedef __bf16 bf16_t;
typedef __bf16 bf16x8 __attribute__((ext_vector_type(8)));
typedef __bf16 bf16x4 __attribute__((ext_vector_type(4)));
typedef float  f32x4  __attribute__((ext_vector_type(4)));

// ---------- helpers ----------

__device__ __forceinline__ void gload16(const void* g, void* lds)
{
    __builtin_amdgcn_global_load_lds(
        (__attribute__((address_space(1))) void*)(void*)g,
        (__attribute__((address_space(3))) void*)lds,
        16, 0, 0);
}

// operands swapped at call sites (mfma(b,a,acc)) -> lane holds 4 CONSECUTIVE
// COLUMNS: C[row = lane&15 (A-frag row)][col = (lane>>4)*4 + r]
__device__ __forceinline__ f32x4 mfma16(bf16x8 a, bf16x8 b, f32x4 c)
{
    return __builtin_amdgcn_mfma_f32_16x16x32_bf16(a, b, c, 0, 0, 0);
}

#define SBAR()   asm volatile("s_barrier" ::: "memory")
#define LGKM0()  asm volatile("s_waitcnt lgkmcnt(0)" ::: "memory")
#define VMCNT(N) asm volatile("s_waitcnt vmcnt(" #N ")" ::: "memory")

// ---------- prep: fused weight casts + dilated gather ----------

__global__ __launch_bounds__(256)
void prep_kernel(const float* __restrict__ Wq, const float* __restrict__ Wk,
                 const float* __restrict__ Wv, const float* __restrict__ Wo,
                 const float* __restrict__ x,
                 bf16_t* __restrict__ Wqkv, bf16_t* __restrict__ Wob,
                 bf16_t* __restrict__ Xe)
{
    const int bid = blockIdx.x;
    const int t = threadIdx.x;
    if (bid < 4096) {
        const int which = bid >> 10;
        const int blk = bid & 1023;
        const float* src = which == 0 ? Wq : which == 1 ? Wk : which == 2 ? Wv : Wo;
        bf16_t* dst = which == 3 ? Wob : Wqkv + (size_t)which * 1048576;
        const size_t i = ((size_t)blk * 256 + t) * 4;
        float4 f = *(const float4*)&src[i];
        bf16x4 o;
        o[0] = (bf16_t)f.x; o[1] = (bf16_t)f.y; o[2] = (bf16_t)f.z; o[3] = (bf16_t)f.w;
        *(bf16x4*)&dst[i] = o;
    } else {
        const int m = bid - 4096;
        const int b = m >> 11, g = (m >> 8) & 7, j = m & 255;
        const float* src = x + ((size_t)b * 4096 + g * 512 + 2 * j) * 1024;
        bf16_t* dst = Xe + (size_t)m * 1024;
        float4 f = *(const float4*)&src[t * 4];
        bf16x4 o;
        o[0] = (bf16_t)f.x; o[1] = (bf16_t)f.y; o[2] = (bf16_t)f.z; o[3] = (bf16_t)f.w;
        *(bf16x4*)&dst[t * 4] = o;
    }
}

// ---------- persistent 256x128 GEMM, BK=32, 2 blocks/CU (K=1024, NSUB sub-tiles) ----------
// grid (8,32) = 256 blocks, XCD-chunked. LDS 48KB (2 bufs x {AL 8K, AH 8K, B 8K})
// -> 2 blocks co-resident per CU so the 2-phase stall of one block hides under
// the other block's MFMA (m114 overlap). Counted vmcnt, never 0 in main loop:
//   P1(t): read A rows 0-63 (per wr unit) + all B; stage AL,AH(t+1) -> other buf
//   P2(t): read A rows 64-127; stage B(t+2) -> cur buf; end vmcnt(1)
// LDS swizzle: granule bits(0-2) ^= granule bits(3-5) (involution both sides).
// EPI: 0 = store bf16; 2 = scatter f32 to even rows of d_out + zero odd rows.
template<int EPI, int NSUB>
__global__ __launch_bounds__(512, 4)
void gemm_mt(const bf16_t* __restrict__ A, const bf16_t* __restrict__ B,
             void* __restrict__ Cv, int lda, int ldb, int ldc)
{
    __shared__ __align__(16) char lds[49152];

    const int tid = threadIdx.x;
    const int w = tid >> 6, lane = tid & 63;
    const int wr = w >> 2, wc = w & 3;
    const int fr = lane & 15, fg = lane >> 4;

    const int lin = blockIdx.y * 8 + blockIdx.x;
    const int L = (lin & 7) * 32 + (lin >> 3);
    const int bm = L >> 3, j = L & 7;
    const int NT = NSUB * 32;

    // stage side: lane tid writes LDS granule tid of an 8KB unit; source
    // granule s = tid ^ ((tid>>3)&7) (involution; matches read-side flip)
    const int s = tid ^ ((tid >> 3) & 7);
    const char* srcA  = (const char*)A + ((size_t)(bm * 256 + (s >> 2)) * lda + (s & 3) * 8) * 2;
    const char* srcB0 = (const char*)B + ((size_t)(j * NSUB * 128 + (s >> 2)) * ldb + (s & 3) * 8) * 2;
    const size_t aHalf  = (size_t)128 * lda * 2;
    const size_t bnStep = (size_t)128 * ldb * 2;
    const int ldsW = w * 1024;

// NOTE: k-tile offset MUST be masked (&31) — T counts across sub-tiles but A's
// K range is one sub-tile (this mask missing was the r8 correctness bug).
#define STG_AL(T) gload16(srcA + (size_t)((T) & 31) * 64,                          \
                          lds + ((T) & 1) * 24576 + ldsW)
#define STG_AH(T) gload16(srcA + aHalf + (size_t)((T) & 31) * 64,                  \
                          lds + ((T) & 1) * 24576 + 8192 + ldsW)
#define STG_B(T)  gload16(srcB0 + (size_t)((T) >> 5) * bnStep + (size_t)((T) & 31) * 64, \
                          lds + ((T) & 1) * 24576 + 16384 + ldsW)

    const int flip = ((fr >> 1) & 7) << 4;           // row bits 1-3 -> byte bits 4-6
    const int aoff = wr * 8192 + fr * 64 + fg * 16;  // + ph*4096 + mi*1024
    const int boff = 16384 + wc * 2048 + fr * 64 + fg * 16;  // + ni*1024

    bf16x8 a[4], b[2];
    f32x4 acc[8][2] = {};

#define LDA(PH, CB) do {                                                        \
    _Pragma("unroll") for (int mi = 0; mi < 4; ++mi)                            \
        a[mi] = *(const bf16x8*)(lds + (CB) +                                   \
            ((aoff + (PH) * 4096 + mi * 1024) ^ flip));                         \
} while (0)

#define LDB(CB) do {                                                            \
    _Pragma("unroll") for (int ni = 0; ni < 2; ++ni)                            \
        b[ni] = *(const bf16x8*)(lds + (CB) +                                   \
            ((boff + ni * 1024) ^ flip));                                       \
} while (0)

#define MF(PH) do {                                                             \
    _Pragma("unroll") for (int mi = 0; mi < 4; ++mi)                            \
    _Pragma("unroll") for (int ni = 0; ni < 2; ++ni)                            \
        acc[(PH) * 4 + mi][ni] =                                                \
            mfma16(b[ni], a[mi], acc[(PH) * 4 + mi][ni]);                       \
} while (0)

    const int r0 = bm * 256 + wr * 128 + fr;
    const int c0w = wc * 32 + fg * 4;

#define DO_EPI(SUB) do {                                                                  \
    const int _c0 = (j * NSUB + (SUB)) * 128 + c0w;                                       \
    if constexpr (EPI == 0) {                                                             \
        bf16_t* C = (bf16_t*)Cv;                                                          \
        _Pragma("unroll") for (int mig = 0; mig < 8; ++mig)                               \
        _Pragma("unroll") for (int ni = 0; ni < 2; ++ni) {                                \
            const int row = r0 + (mig >> 2) * 64 + (mig & 3) * 16;                        \
            bf16x4 o;                                                                     \
            _Pragma("unroll") for (int r = 0; r < 4; ++r) o[r] = (bf16_t)acc[mig][ni][r]; \
            *(bf16x4*)&C[(size_t)row * ldc + _c0 + ni * 16] = o;                          \
        }                                                                                 \
    } else {                                                                              \
        float* C = (float*)Cv;                                                            \
        const f32x4 z4 = {0.f, 0.f, 0.f, 0.f};                                            \
        _Pragma("unroll") for (int mig = 0; mig < 8; ++mig)                               \
        _Pragma("unroll") for (int ni = 0; ni < 2; ++ni) {                                \
            const int m  = r0 + (mig >> 2) * 64 + (mig & 3) * 16;                         \
            const int gr = ((m >> 11) << 12) | (((m >> 8) & 7) << 9) | ((m & 255) << 1);  \
            *(f32x4*)&C[(size_t)gr * 1024 + _c0 + ni * 16]       = acc[mig][ni];          \
            *(f32x4*)&C[(size_t)(gr + 1) * 1024 + _c0 + ni * 16] = z4;                    \
        }                                                                                 \
    }                                                                                     \
    _Pragma("unroll") for (int mig = 0; mig < 8; ++mig)                                   \
    _Pragma("unroll") for (int ni = 0; ni < 2; ++ni)                                      \
        acc[mig][ni] = (f32x4){0.f, 0.f, 0.f, 0.f};                                       \
} while (0)

    // prologue: tile0 {AL,AH,B} + B(1); wait tile0 landed (vmcnt(1))
    STG_AL(0); STG_AH(0); STG_B(0);
    STG_B(1);
    VMCNT(1);
    SBAR();

    for (int t = 0; t <= NT - 3; ++t) {
        const int cb = (t & 1) * 24576;
        // P1
        LDA(0, cb); LDB(cb);
        STG_AL(t + 1); STG_AH(t + 1);
        SBAR(); LGKM0();
        __builtin_amdgcn_s_setprio(1); MF(0); __builtin_amdgcn_s_setprio(0);
        VMCNT(3);
        SBAR();
        // P2
        LDA(1, cb);
        STG_B(t + 2);
        SBAR(); LGKM0();
        __builtin_amdgcn_s_setprio(1); MF(1); __builtin_amdgcn_s_setprio(0);
        VMCNT(1);
        if ((t & 31) == 31) DO_EPI(t >> 5);
        SBAR();
    }

    // tile NT-2: stage AL,AH(NT-1); drain fully at end
    {
        const int cb = ((NT - 2) & 1) * 24576;
        LDA(0, cb); LDB(cb);
        STG_AL(NT - 1); STG_AH(NT - 1);
        SBAR(); LGKM0();
        MF(0);
        VMCNT(3);
        SBAR();
        LDA(1, cb);
        SBAR(); LGKM0();
        MF(1);
        VMCNT(0);
        SBAR();
    }
    // tile NT-1: everything resident
    {
        const int cb = ((NT - 1) & 1) * 24576;
        LDA(0, cb); LDB(cb);
        LGKM0();
        MF(0);
        LDA(1, cb);
        LGKM0();
        MF(1);
    }
    DO_EPI(NSUB - 1);

#undef STG_AL
#undef STG_AH
#undef STG_B
#undef LDA
#undef LDB
#undef MF
#undef DO_EPI
}

// ---------- GEMM: C[M,N] = A[M,K] * B[N,K]^T (128x128 tile, swizzled m97) ----------
// flags bit0 = triangular-A K-skip (bm==0 -> K/2). Used for PV.
template<int EPI>   // 0 = store bf16, 1 = store f32
__global__ __launch_bounds__(256)
void gemm_nt(const bf16_t* __restrict__ A, const bf16_t* __restrict__ B,
             void* __restrict__ Cv,
             int K, int lda, int ldb, int ldc,
             long sA, long sB, long sC, int flags)
{
    __shared__ __align__(16) bf16_t Asm[128 * 32];
    __shared__ __align__(16) bf16_t Bsm[128 * 32];

    const int bn = blockIdx.x, bm = blockIdx.y, bz = blockIdx.z;
    const int tid  = threadIdx.x;
    const int wave = tid >> 6;
    const int lane = tid & 63;
    const int wr = wave >> 1, wc = wave & 1;

    const bf16_t* Ab = A + (long)bz * sA;
    const bf16_t* Bb = B + (long)bz * sB;

    const int Keff = ((flags & 1) && bm == 0) ? (K >> 1) : K;

    const int sw0 = tid ^ ((tid >> 3) & 3);
    const int dd1 = tid + 256;
    const int sw1 = dd1 ^ ((dd1 >> 3) & 3);
    const bf16_t* a0 = Ab + (size_t)(bm * 128 + (sw0 >> 2)) * lda + (sw0 & 3) * 8;
    const bf16_t* a1 = Ab + (size_t)(bm * 128 + (sw1 >> 2)) * lda + (sw1 & 3) * 8;
    const bf16_t* b0 = Bb + (size_t)(bn * 128 + (sw0 >> 2)) * ldb + (sw0 & 3) * 8;
    const bf16_t* b1 = Bb + (size_t)(bn * 128 + (sw1 >> 2)) * ldb + (sw1 & 3) * 8;
    char* ldsA = (char*)Asm + wave * 1024;
    char* ldsB = (char*)Bsm + wave * 1024;

    f32x4 acc[4][4] = {};

    const int frow = lane & 15;
    const int fk   = (lane >> 4) * 8;
    const int flip = (frow & 6) << 2;

    for (int k0 = 0; k0 < Keff; k0 += 32) {
        gload16(a0, ldsA);
        gload16(a1, ldsA + 4096);
        gload16(b0, ldsB);
        gload16(b1, ldsB + 4096);
        a0 += 32; a1 += 32; b0 += 32; b1 += 32;
        __syncthreads();

        bf16x8 af[4], bfr[4];
#pragma unroll
        for (int mi = 0; mi < 4; ++mi)
            af[mi] = *(const bf16x8*)&Asm[(size_t)(((wr * 64 + mi * 16 + frow) * 32 + fk) ^ flip)];
#pragma unroll
        for (int ni = 0; ni < 4; ++ni)
            bfr[ni] = *(const bf16x8*)&Bsm[(size_t)(((wc * 64 + ni * 16 + frow) * 32 + fk) ^ flip)];
#pragma unroll
        for (int mi = 0; mi < 4; ++mi)
#pragma unroll
            for (int ni = 0; ni < 4; ++ni)
                acc[mi][ni] = mfma16(bfr[ni], af[mi], acc[mi][ni]);   // swapped
        __syncthreads();
    }

    const int row0 = bm * 128 + wr * 64 + frow;
    const int col0 = bn * 128 + wc * 64 + (lane >> 4) * 4;

    if constexpr (EPI == 0) {
        bf16_t* C = (bf16_t*)Cv + (long)bz * sC;
#pragma unroll
        for (int mi = 0; mi < 4; ++mi)
#pragma unroll
            for (int ni = 0; ni < 4; ++ni) {
                bf16x4 o;
#pragma unroll
                for (int r = 0; r < 4; ++r) o[r] = (bf16_t)acc[mi][ni][r];
                *(bf16x4*)&C[(size_t)(row0 + mi * 16) * ldc + col0 + ni * 16] = o;
            }
    } else {
        float* C = (float*)Cv + (long)bz * sC;
#pragma unroll
        for (int mi = 0; mi < 4; ++mi)
#pragma unroll
            for (int ni = 0; ni < 4; ++ni)
                *(f32x4*)&C[(size_t)(row0 + mi * 16) * ldc + col0 + ni * 16] = acc[mi][ni];
    }
}

// ---------- fused QK^T + causal softmax (device body) ----------
// 512 thr / 8 waves (2 wr x 4 wc). NI=4 -> block N=256 (qb1); NI=2 -> N=128 (qb0).
template<int NI>
__device__ __forceinline__ void qk_block(
    const bf16_t* __restrict__ Ab, const bf16_t* __restrict__ Bb,
    bf16_t* __restrict__ Pseg, int qb, char* smem, int tid)
{
    bf16_t* Asm = (bf16_t*)smem;                 // [128][32]
    bf16_t* Bsm = (bf16_t*)(smem + 8192);        // [NI*64][32]
    float*  red = (float*)(smem + 24576);        // [128][4]

    const int w = tid >> 6, lane = tid & 63;
    const int wr = w >> 2, wc = w & 3;
    const int frow = lane & 15, fg = lane >> 4;

    const int g0 = tid, g1 = tid + 512;
    const int s0 = g0 ^ ((g0 >> 3) & 3);
    const int s1 = g1 ^ ((g1 >> 3) & 3);
    const bf16_t* a0 = Ab + (size_t)(s0 >> 2) * 3072 + (s0 & 3) * 8;
    const bf16_t* b0 = Bb + (size_t)(s0 >> 2) * 3072 + (s0 & 3) * 8;
    const bf16_t* b1 = Bb + (size_t)(s1 >> 2) * 3072 + (s1 & 3) * 8;
    char* ldsA = smem + w * 1024;
    char* ldsB = smem + 8192 + w * 1024;

    f32x4 acc[4][NI] = {};
    const int fk = fg * 8;
    const int flip = (frow & 6) << 2;
    const int Nw = NI * 16;

    for (int k0 = 0; k0 < 1024; k0 += 32) {
        gload16(a0, ldsA);
        gload16(b0, ldsB);
        if (NI == 4) gload16(b1, ldsB + 8192);
        a0 += 32; b0 += 32; b1 += 32;
        __syncthreads();

        bf16x8 af[4], bf_[NI];
#pragma unroll
        for (int mi = 0; mi < 4; ++mi)
            af[mi] = *(const bf16x8*)&Asm[((wr * 64 + mi * 16 + frow) * 32 + fk) ^ flip];
#pragma unroll
        for (int ni = 0; ni < NI; ++ni)
            bf_[ni] = *(const bf16x8*)&Bsm[((wc * Nw + ni * 16 + frow) * 32 + fk) ^ flip];
#pragma unroll
        for (int mi = 0; mi < 4; ++mi)
#pragma unroll
            for (int ni = 0; ni < NI; ++ni)
                acc[mi][ni] = mfma16(bf_[ni], af[mi], acc[mi][ni]);   // swapped
        __syncthreads();
    }

    // ---- softmax epilogue ----
    const int base_rloc = wr * 64 + frow;
    const float scale = 1.0f / 32.0f;

#pragma unroll
    for (int mi = 0; mi < 4; ++mi) {
        const int rl = base_rloc + mi * 16;
        const int grow = qb * 128 + rl;
        float m = -3.0e38f;
#pragma unroll
        for (int ni = 0; ni < NI; ++ni)
#pragma unroll
            for (int r = 0; r < 4; ++r) {
                const int col = wc * Nw + ni * 16 + fg * 4 + r;
                float v = acc[mi][ni][r] * scale;
                if (col > grow) v = -3.0e38f;
                acc[mi][ni][r] = v;
                m = fmaxf(m, v);
            }
        m = fmaxf(m, __shfl_xor(m, 16));
        m = fmaxf(m, __shfl_xor(m, 32));
        if (fg == 0) red[rl * 4 + wc] = m;
    }
    __syncthreads();
    float mx[4];
#pragma unroll
    for (int mi = 0; mi < 4; ++mi) {
        const int rl = base_rloc + mi * 16;
        mx[mi] = fmaxf(fmaxf(red[rl * 4 + 0], red[rl * 4 + 1]),
                       fmaxf(red[rl * 4 + 2], red[rl * 4 + 3]));
    }
    __syncthreads();

#pragma unroll
    for (int mi = 0; mi < 4; ++mi) {
        const int rl = base_rloc + mi * 16;
        float s = 0.f;
#pragma unroll
        for (int ni = 0; ni < NI; ++ni)
#pragma unroll
            for (int r = 0; r < 4; ++r) {
                const float e = __expf(acc[mi][ni][r] - mx[mi]);
                acc[mi][ni][r] = e;
                s += e;
            }
        s += __shfl_xor(s, 16);
        s += __shfl_xor(s, 32);
        if (fg == 0) red[rl * 4 + wc] = s;
    }
    __syncthreads();

#pragma unroll
    for (int mi = 0; mi < 4; ++mi) {
        const int rl = base_rloc + mi * 16;
        const float inv = 1.0f / (red[rl * 4 + 0] + red[rl * 4 + 1] +
                                  red[rl * 4 + 2] + red[rl * 4 + 3]);
        const int grow = qb * 128 + rl;
#pragma unroll
        for (int ni = 0; ni < NI; ++ni) {
            bf16x4 o;
#pragma unroll
            for (int r = 0; r < 4; ++r) o[r] = (bf16_t)(acc[mi][ni][r] * inv);
            *(bf16x4*)&Pseg[(size_t)grow * 256 + wc * Nw + ni * 16 + fg * 4] = o;
        }
    }
}

// ---------- merged: fused QK^T+softmax (blocks 0..63) + V transpose (rest) ----------
__global__ __launch_bounds__(512)
void qk_sm_tr_kernel(const bf16_t* __restrict__ qkv, bf16_t* __restrict__ P,
                     bf16_t* __restrict__ Vt)
{
    __shared__ __align__(16) char smem[26624];
    const int bid = blockIdx.x;
    const int tid = threadIdx.x;

    if (bid < 64) {
        const int seg = bid >> 1, qb = bid & 1;
        const bf16_t* Ab = qkv + (size_t)seg * 786432 + (size_t)qb * 128 * 3072;
        const bf16_t* Bb = qkv + (size_t)seg * 786432 + 1024;
        bf16_t* Pseg = P + (size_t)seg * 65536;
        if (qb) qk_block<4>(Ab, Bb, Pseg, 1, smem, tid);
        else    qk_block<2>(Ab, Bb, Pseg, 0, smem, tid);
    } else {
        const int id2 = bid - 64;
        const int seg = id2 >> 6;
        const int rem = id2 & 63;
        const int eb = rem >> 2, kb = rem & 3;
        bf16_t* tile = (bf16_t*)smem;   // [64][65]
        const int rr = tid >> 3, cs = (tid & 7) * 8;
        const bf16_t* src = qkv + ((size_t)seg * 256 + kb * 64 + rr) * 3072
                                + 2048 + eb * 64 + cs;
        bf16x8 v = *(const bf16x8*)src;
#pragma unroll
        for (int i = 0; i < 8; ++i) tile[rr * 65 + cs + i] = v[i];
        __syncthreads();
        bf16x8 o;
#pragma unroll
        for (int i = 0; i < 8; ++i) o[i] = tile[(cs + i) * 65 + rr];
        *(bf16x8*)&Vt[(size_t)seg * 262144 + (size_t)(eb * 64 + rr) * 256 + kb * 64 + cs] = o;
    }
}

// ---------- LayerNorm (in place, bf16x8, 2 rows per block) ----------
__global__ __launch_bounds__(256)
void ln_kernel(bf16_t* __restrict__ qkv,
               const float* __restrict__ gamma, const float* __restrict__ beta)
{
    const int t = threadIdx.x;
    const int r = t >> 7;
    const int row = blockIdx.x * 2 + r;
    const int which = blockIdx.y;
    bf16_t* p = qkv + (size_t)row * 3072 + which * 1024;
    const int li = t & 127;
    const int c0 = li * 8;

    bf16x8 v = *(const bf16x8*)&p[c0];
    float f[8];
    float s = 0.f, ss = 0.f;
#pragma unroll
    for (int i = 0; i < 8; ++i) { f[i] = (float)v[i]; s += f[i]; ss += f[i] * f[i]; }
#pragma unroll
    for (int o = 32; o; o >>= 1) { s += __shfl_xor(s, o); ss += __shfl_xor(ss, o); }

    __shared__ float rs_[4], rss_[4];
    const int wave = t >> 6, lane = t & 63;
    if (lane == 0) { rs_[wave] = s; rss_[wave] = ss; }
    __syncthreads();
    s  = rs_[2 * r] + rs_[2 * r + 1];
    ss = rss_[2 * r] + rss_[2 * r + 1];

    const float mu   = s * (1.f / 1024.f);
    const float var  = ss * (1.f / 1024.f) - mu * mu;
    const float rstd = rsqrtf(var + 1e-5f);

    bf16x8 o;
#pragma unroll
    for (int i = 0; i < 8; ++i)
        o[i] = (bf16_t)((f[i] - mu) * rstd * gamma[c0 + i] + beta[c0 + i]);
    *(bf16x8*)&p[c0] = o;
}

// ---------- launch ----------

extern "C" void kernel_launch(void* const* d_in, const int* in_sizes, int n_in,
                              void* d_out, int out_size, void* d_ws, size_t ws_size,
                              hipStream_t stream)
{
    const float* x     = (const float*)d_in[0];
    const float* Wq    = (const float*)d_in[1];
    const float* Wk    = (const float*)d_in[2];
    const float* Wv    = (const float*)d_in[3];
    const float* Wo    = (const float*)d_in[4];
    const float* gamma = (const float*)d_in[5];
    const float* beta  = (const float*)d_in[6];
    float* out = (float*)d_out;

    char* ws = (char*)d_ws;
    bf16_t* Xe   = (bf16_t*)(ws);                  // 8192x1024 bf16   (16 MB)
    bf16_t* Wqkv = (bf16_t*)(ws + (16u  << 20));   // 3072x1024 bf16   ( 6 MB)
    bf16_t* Wob  = (bf16_t*)(ws + (22u  << 20));   // 1024x1024 bf16   ( 2 MB)
    bf16_t* QKV  = (bf16_t*)(ws + (24u  << 20));   // 8192x3072 bf16   (48 MB)
    bf16_t* P    = (bf16_t*)(ws + (80u  << 20));   // 32x256x256 bf16  ( 4 MB)
    bf16_t* Vt   = (bf16_t*)(ws + (84u  << 20));   // 32x1024x256 bf16 (16 MB)
    bf16_t* Y    = (bf16_t*)(ws + (100u << 20));   // 8192x1024 bf16   (16 MB)

    // prep: weight casts + dilated gather (one launch)
    prep_kernel<<<12288, 256, 0, stream>>>(Wq, Wk, Wv, Wo, x, Wqkv, Wob, Xe);

    // QKV projection: persistent 2-phase BK=32, 2 blocks/CU, XCD-chunked
    gemm_mt<0, 3><<<dim3(8, 32), 512, 0, stream>>>(
        Xe, Wqkv, QKV, 1024, 1024, 3072);

    // LayerNorm q,k,v in place
    ln_kernel<<<dim3(4096, 3), 256, 0, stream>>>(QKV, gamma, beta);

    // fused: S = QK^T -> causal softmax -> P (direct), plus V transpose
    qk_sm_tr_kernel<<<64 + 2048, 512, 0, stream>>>(QKV, P, Vt);

    // Y = P V per segment (tri: bm==0 blocks only need K=128)
    gemm_nt<0><<<dim3(8, 2, 32), 256, 0, stream>>>(
        P, Vt, Y, 256, 256, 256, 1024,
        65536L, 262144L, 262144L, 1);

    // out = Y Wo^T scattered to even rows of d_out, odd rows zeroed
    gemm_mt<2, 1><<<dim3(8, 32), 512, 0, stream>>>(
        Y, Wob, out, 1024, 1024, 1024);
}

// Round 10
// 176.697 us; speedup vs baseline: 1.0128x; 1.0128x over previous
//
#include <hip/hip_runtime.h>
#include <stdint.h>

typedef __bf16 bf16_t;
typedef __bf16 bf16x8 __attribute__((ext_vector_type(8)));
typedef __bf16 bf16x4 __attribute__((ext_vector_type(4)));
typedef float  f32x4  __attribute__((ext_vector_type(4)));

// ---------- helpers ----------

__device__ __forceinline__ void gload16(const void* g, void* lds)
{
    __builtin_amdgcn_global_load_lds(
        (__attribute__((address_space(1))) void*)(void*)g,
        (__attribute__((address_space(3))) void*)lds,
        16, 0, 0);
}

// operands swapped at call sites (mfma(b,a,acc)) -> lane holds 4 CONSECUTIVE
// COLUMNS: C[row = lane&15 (A-frag row)][col = (lane>>4)*4 + r]
__device__ __forceinline__ f32x4 mfma16(bf16x8 a, bf16x8 b, f32x4 c)
{
    return __builtin_amdgcn_mfma_f32_16x16x32_bf16(a, b, c, 0, 0, 0);
}

#define SBAR()   asm volatile("s_barrier" ::: "memory")
#define LGKM0()  asm volatile("s_waitcnt lgkmcnt(0)" ::: "memory")
#define VMCNT(N) asm volatile("s_waitcnt vmcnt(" #N ")" ::: "memory")

// ---------- prep: fused weight casts + dilated gather ----------

__global__ __launch_bounds__(256)
void prep_kernel(const float* __restrict__ Wq, const float* __restrict__ Wk,
                 const float* __restrict__ Wv, const float* __restrict__ Wo,
                 const float* __restrict__ x,
                 bf16_t* __restrict__ Wqkv, bf16_t* __restrict__ Wob,
                 bf16_t* __restrict__ Xe)
{
    const int bid = blockIdx.x;
    const int t = threadIdx.x;
    if (bid < 4096) {
        const int which = bid >> 10;
        const int blk = bid & 1023;
        const float* src = which == 0 ? Wq : which == 1 ? Wk : which == 2 ? Wv : Wo;
        bf16_t* dst = which == 3 ? Wob : Wqkv + (size_t)which * 1048576;
        const size_t i = ((size_t)blk * 256 + t) * 4;
        float4 f = *(const float4*)&src[i];
        bf16x4 o;
        o[0] = (bf16_t)f.x; o[1] = (bf16_t)f.y; o[2] = (bf16_t)f.z; o[3] = (bf16_t)f.w;
        *(bf16x4*)&dst[i] = o;
    } else {
        const int m = bid - 4096;
        const int b = m >> 11, g = (m >> 8) & 7, j = m & 255;
        const float* src = x + ((size_t)b * 4096 + g * 512 + 2 * j) * 1024;
        bf16_t* dst = Xe + (size_t)m * 1024;
        float4 f = *(const float4*)&src[t * 4];
        bf16x4 o;
        o[0] = (bf16_t)f.x; o[1] = (bf16_t)f.y; o[2] = (bf16_t)f.z; o[3] = (bf16_t)f.w;
        *(bf16x4*)&dst[t * 4] = o;
    }
}

// ---------- 256x128 GEMM, BK=32, LDS 48KB -> up to 3 blocks/CU ----------
// Generic grid (gx, gy): bm = 0..gy-1 (256 rows), j = 0..gx-1 (128 cols),
// NSUB sub-tiles per block (QKV uses gx=24, NSUB=1 -> 768 blocks = 3/CU
// co-resident; their independent pipelines overlap stall phases, m114).
// XCD-chunked bijective swizzle, j-fastest so consecutive blocks share A-panel.
// Counted vmcnt, never 0 in main loop:
//   P1(t): read A 0-63 + B; stage AL,AH(t+1) -> other buf; end vmcnt(3)
//   P2(t): read A 64-127; stage B(t+2) -> cur buf; end vmcnt(1)
// LDS swizzle: granule bits(0-2) ^= (3-5) per 8KB unit (0-conflict, r3).
// EPI: 0 = store bf16; 2 = scatter f32 to even rows of d_out + zero odd rows.
template<int EPI, int NSUB>
__global__ __launch_bounds__(512, 4)
void gemm_mt(const bf16_t* __restrict__ A, const bf16_t* __restrict__ B,
             void* __restrict__ Cv, int lda, int ldb, int ldc)
{
    __shared__ __align__(16) char lds[49152];

    const int tid = threadIdx.x;
    const int w = tid >> 6, lane = tid & 63;
    const int wr = w >> 2, wc = w & 3;
    const int fr = lane & 15, fg = lane >> 4;

    const int gx = gridDim.x;
    const int lin = blockIdx.y * gx + blockIdx.x;
    const int cpx = (gx * gridDim.y) >> 3;
    const int L = (lin & 7) * cpx + (lin >> 3);
    const int bm = L / gx;
    const int j = L - bm * gx;
    const int NT = NSUB * 32;

    // stage side: lane tid writes LDS granule tid of an 8KB unit; source
    // granule s = tid ^ ((tid>>3)&7) (involution; matches read-side flip)
    const int s = tid ^ ((tid >> 3) & 7);
    const char* srcA  = (const char*)A + ((size_t)(bm * 256 + (s >> 2)) * lda + (s & 3) * 8) * 2;
    const char* srcB0 = (const char*)B + ((size_t)(j * NSUB * 128 + (s >> 2)) * ldb + (s & 3) * 8) * 2;
    const size_t aHalf  = (size_t)128 * lda * 2;
    const size_t bnStep = (size_t)128 * ldb * 2;
    const int ldsW = w * 1024;

// k-tile offset masked (&31): T counts across sub-tiles, A's K range is one sub-tile.
#define STG_AL(T) gload16(srcA + (size_t)((T) & 31) * 64,                          \
                          lds + ((T) & 1) * 24576 + ldsW)
#define STG_AH(T) gload16(srcA + aHalf + (size_t)((T) & 31) * 64,                  \
                          lds + ((T) & 1) * 24576 + 8192 + ldsW)
#define STG_B(T)  gload16(srcB0 + (size_t)((T) >> 5) * bnStep + (size_t)((T) & 31) * 64, \
                          lds + ((T) & 1) * 24576 + 16384 + ldsW)

    const int flip = ((fr >> 1) & 7) << 4;           // row bits 1-3 -> byte bits 4-6
    const int aoff = wr * 8192 + fr * 64 + fg * 16;  // + ph*4096 + mi*1024
    const int boff = 16384 + wc * 2048 + fr * 64 + fg * 16;  // + ni*1024

    bf16x8 a[4], b[2];
    f32x4 acc[8][2] = {};

#define LDA(PH, CB) do {                                                        \
    _Pragma("unroll") for (int mi = 0; mi < 4; ++mi)                            \
        a[mi] = *(const bf16x8*)(lds + (CB) +                                   \
            ((aoff + (PH) * 4096 + mi * 1024) ^ flip));                         \
} while (0)

#define LDB(CB) do {                                                            \
    _Pragma("unroll") for (int ni = 0; ni < 2; ++ni)                            \
        b[ni] = *(const bf16x8*)(lds + (CB) +                                   \
            ((boff + ni * 1024) ^ flip));                                       \
} while (0)

#define MF(PH) do {                                                             \
    _Pragma("unroll") for (int mi = 0; mi < 4; ++mi)                            \
    _Pragma("unroll") for (int ni = 0; ni < 2; ++ni)                            \
        acc[(PH) * 4 + mi][ni] =                                                \
            mfma16(b[ni], a[mi], acc[(PH) * 4 + mi][ni]);                       \
} while (0)

    const int r0 = bm * 256 + wr * 128 + fr;
    const int c0w = wc * 32 + fg * 4;

#define DO_EPI(SUB) do {                                                                  \
    const int _c0 = (j * NSUB + (SUB)) * 128 + c0w;                                       \
    if constexpr (EPI == 0) {                                                             \
        bf16_t* C = (bf16_t*)Cv;                                                          \
        _Pragma("unroll") for (int mig = 0; mig < 8; ++mig)                               \
        _Pragma("unroll") for (int ni = 0; ni < 2; ++ni) {                                \
            const int row = r0 + (mig >> 2) * 64 + (mig & 3) * 16;                        \
            bf16x4 o;                                                                     \
            _Pragma("unroll") for (int r = 0; r < 4; ++r) o[r] = (bf16_t)acc[mig][ni][r]; \
            *(bf16x4*)&C[(size_t)row * ldc + _c0 + ni * 16] = o;                          \
        }                                                                                 \
    } else {                                                                              \
        float* C = (float*)Cv;                                                            \
        const f32x4 z4 = {0.f, 0.f, 0.f, 0.f};                                            \
        _Pragma("unroll") for (int mig = 0; mig < 8; ++mig)                               \
        _Pragma("unroll") for (int ni = 0; ni < 2; ++ni) {                                \
            const int m  = r0 + (mig >> 2) * 64 + (mig & 3) * 16;                         \
            const int gr = ((m >> 11) << 12) | (((m >> 8) & 7) << 9) | ((m & 255) << 1);  \
            *(f32x4*)&C[(size_t)gr * 1024 + _c0 + ni * 16]       = acc[mig][ni];          \
            *(f32x4*)&C[(size_t)(gr + 1) * 1024 + _c0 + ni * 16] = z4;                    \
        }                                                                                 \
    }                                                                                     \
    _Pragma("unroll") for (int mig = 0; mig < 8; ++mig)                                   \
    _Pragma("unroll") for (int ni = 0; ni < 2; ++ni)                                      \
        acc[mig][ni] = (f32x4){0.f, 0.f, 0.f, 0.f};                                       \
} while (0)

    // prologue: tile0 {AL,AH,B} + B(1); wait tile0 landed (vmcnt(1))
    STG_AL(0); STG_AH(0); STG_B(0);
    STG_B(1);
    VMCNT(1);
    SBAR();

    for (int t = 0; t <= NT - 3; ++t) {
        const int cb = (t & 1) * 24576;
        // P1
        LDA(0, cb); LDB(cb);
        STG_AL(t + 1); STG_AH(t + 1);
        SBAR(); LGKM0();
        __builtin_amdgcn_s_setprio(1); MF(0); __builtin_amdgcn_s_setprio(0);
        VMCNT(3);
        SBAR();
        // P2
        LDA(1, cb);
        STG_B(t + 2);
        SBAR(); LGKM0();
        __builtin_amdgcn_s_setprio(1); MF(1); __builtin_amdgcn_s_setprio(0);
        VMCNT(1);
        if (NSUB > 1 && (t & 31) == 31) DO_EPI(t >> 5);
        SBAR();
    }

    // tile NT-2: stage AL,AH(NT-1); drain fully at end
    {
        const int cb = ((NT - 2) & 1) * 24576;
        LDA(0, cb); LDB(cb);
        STG_AL(NT - 1); STG_AH(NT - 1);
        SBAR(); LGKM0();
        MF(0);
        VMCNT(3);
        SBAR();
        LDA(1, cb);
        SBAR(); LGKM0();
        MF(1);
        VMCNT(0);
        SBAR();
    }
    // tile NT-1: everything resident
    {
        const int cb = ((NT - 1) & 1) * 24576;
        LDA(0, cb); LDB(cb);
        LGKM0();
        MF(0);
        LDA(1, cb);
        LGKM0();
        MF(1);
    }
    DO_EPI(NSUB - 1);

#undef STG_AL
#undef STG_AH
#undef STG_B
#undef LDA
#undef LDB
#undef MF
#undef DO_EPI
}

// ---------- GEMM: C[M,N] = A[M,K] * B[N,K]^T (128x128 tile, swizzled m97) ----------
// flags bit0 = triangular-A K-skip (bm==0 -> K/2). Used for PV.
template<int EPI>   // 0 = store bf16, 1 = store f32
__global__ __launch_bounds__(256)
void gemm_nt(const bf16_t* __restrict__ A, const bf16_t* __restrict__ B,
             void* __restrict__ Cv,
             int K, int lda, int ldb, int ldc,
             long sA, long sB, long sC, int flags)
{
    __shared__ __align__(16) bf16_t Asm[128 * 32];
    __shared__ __align__(16) bf16_t Bsm[128 * 32];

    const int bn = blockIdx.x, bm = blockIdx.y, bz = blockIdx.z;
    const int tid  = threadIdx.x;
    const int wave = tid >> 6;
    const int lane = tid & 63;
    const int wr = wave >> 1, wc = wave & 1;

    const bf16_t* Ab = A + (long)bz * sA;
    const bf16_t* Bb = B + (long)bz * sB;

    const int Keff = ((flags & 1) && bm == 0) ? (K >> 1) : K;

    const int sw0 = tid ^ ((tid >> 3) & 3);
    const int dd1 = tid + 256;
    const int sw1 = dd1 ^ ((dd1 >> 3) & 3);
    const bf16_t* a0 = Ab + (size_t)(bm * 128 + (sw0 >> 2)) * lda + (sw0 & 3) * 8;
    const bf16_t* a1 = Ab + (size_t)(bm * 128 + (sw1 >> 2)) * lda + (sw1 & 3) * 8;
    const bf16_t* b0 = Bb + (size_t)(bn * 128 + (sw0 >> 2)) * ldb + (sw0 & 3) * 8;
    const bf16_t* b1 = Bb + (size_t)(bn * 128 + (sw1 >> 2)) * ldb + (sw1 & 3) * 8;
    char* ldsA = (char*)Asm + wave * 1024;
    char* ldsB = (char*)Bsm + wave * 1024;

    f32x4 acc[4][4] = {};

    const int frow = lane & 15;
    const int fk   = (lane >> 4) * 8;
    const int flip = (frow & 6) << 2;

    for (int k0 = 0; k0 < Keff; k0 += 32) {
        gload16(a0, ldsA);
        gload16(a1, ldsA + 4096);
        gload16(b0, ldsB);
        gload16(b1, ldsB + 4096);
        a0 += 32; a1 += 32; b0 += 32; b1 += 32;
        __syncthreads();

        bf16x8 af[4], bfr[4];
#pragma unroll
        for (int mi = 0; mi < 4; ++mi)
            af[mi] = *(const bf16x8*)&Asm[(size_t)(((wr * 64 + mi * 16 + frow) * 32 + fk) ^ flip)];
#pragma unroll
        for (int ni = 0; ni < 4; ++ni)
            bfr[ni] = *(const bf16x8*)&Bsm[(size_t)(((wc * 64 + ni * 16 + frow) * 32 + fk) ^ flip)];
#pragma unroll
        for (int mi = 0; mi < 4; ++mi)
#pragma unroll
            for (int ni = 0; ni < 4; ++ni)
                acc[mi][ni] = mfma16(bfr[ni], af[mi], acc[mi][ni]);   // swapped
        __syncthreads();
    }

    const int row0 = bm * 128 + wr * 64 + frow;
    const int col0 = bn * 128 + wc * 64 + (lane >> 4) * 4;

    if constexpr (EPI == 0) {
        bf16_t* C = (bf16_t*)Cv + (long)bz * sC;
#pragma unroll
        for (int mi = 0; mi < 4; ++mi)
#pragma unroll
            for (int ni = 0; ni < 4; ++ni) {
                bf16x4 o;
#pragma unroll
                for (int r = 0; r < 4; ++r) o[r] = (bf16_t)acc[mi][ni][r];
                *(bf16x4*)&C[(size_t)(row0 + mi * 16) * ldc + col0 + ni * 16] = o;
            }
    } else {
        float* C = (float*)Cv + (long)bz * sC;
#pragma unroll
        for (int mi = 0; mi < 4; ++mi)
#pragma unroll
            for (int ni = 0; ni < 4; ++ni)
                *(f32x4*)&C[(size_t)(row0 + mi * 16) * ldc + col0 + ni * 16] = acc[mi][ni];
    }
}

// ---------- fused QK^T + causal softmax (device body) ----------
// 512 thr / 8 waves (2 wr x 4 wc). NI=4 -> block N=256 (qb1); NI=2 -> N=128 (qb0).
template<int NI>
__device__ __forceinline__ void qk_block(
    const bf16_t* __restrict__ Ab, const bf16_t* __restrict__ Bb,
    bf16_t* __restrict__ Pseg, int qb, char* smem, int tid)
{
    bf16_t* Asm = (bf16_t*)smem;                 // [128][32]
    bf16_t* Bsm = (bf16_t*)(smem + 8192);        // [NI*64][32]
    float*  red = (float*)(smem + 24576);        // [128][4]

    const int w = tid >> 6, lane = tid & 63;
    const int wr = w >> 2, wc = w & 3;
    const int frow = lane & 15, fg = lane >> 4;

    const int g0 = tid, g1 = tid + 512;
    const int s0 = g0 ^ ((g0 >> 3) & 3);
    const int s1 = g1 ^ ((g1 >> 3) & 3);
    const bf16_t* a0 = Ab + (size_t)(s0 >> 2) * 3072 + (s0 & 3) * 8;
    const bf16_t* b0 = Bb + (size_t)(s0 >> 2) * 3072 + (s0 & 3) * 8;
    const bf16_t* b1 = Bb + (size_t)(s1 >> 2) * 3072 + (s1 & 3) * 8;
    char* ldsA = smem + w * 1024;
    char* ldsB = smem + 8192 + w * 1024;

    f32x4 acc[4][NI] = {};
    const int fk = fg * 8;
    const int flip = (frow & 6) << 2;
    const int Nw = NI * 16;

    for (int k0 = 0; k0 < 1024; k0 += 32) {
        gload16(a0, ldsA);
        gload16(b0, ldsB);
        if (NI == 4) gload16(b1, ldsB + 8192);
        a0 += 32; b0 += 32; b1 += 32;
        __syncthreads();

        bf16x8 af[4], bf_[NI];
#pragma unroll
        for (int mi = 0; mi < 4; ++mi)
            af[mi] = *(const bf16x8*)&Asm[((wr * 64 + mi * 16 + frow) * 32 + fk) ^ flip];
#pragma unroll
        for (int ni = 0; ni < NI; ++ni)
            bf_[ni] = *(const bf16x8*)&Bsm[((wc * Nw + ni * 16 + frow) * 32 + fk) ^ flip];
#pragma unroll
        for (int mi = 0; mi < 4; ++mi)
#pragma unroll
            for (int ni = 0; ni < NI; ++ni)
                acc[mi][ni] = mfma16(bf_[ni], af[mi], acc[mi][ni]);   // swapped
        __syncthreads();
    }

    // ---- softmax epilogue ----
    const int base_rloc = wr * 64 + frow;
    const float scale = 1.0f / 32.0f;

#pragma unroll
    for (int mi = 0; mi < 4; ++mi) {
        const int rl = base_rloc + mi * 16;
        const int grow = qb * 128 + rl;
        float m = -3.0e38f;
#pragma unroll
        for (int ni = 0; ni < NI; ++ni)
#pragma unroll
            for (int r = 0; r < 4; ++r) {
                const int col = wc * Nw + ni * 16 + fg * 4 + r;
                float v = acc[mi][ni][r] * scale;
                if (col > grow) v = -3.0e38f;
                acc[mi][ni][r] = v;
                m = fmaxf(m, v);
            }
        m = fmaxf(m, __shfl_xor(m, 16));
        m = fmaxf(m, __shfl_xor(m, 32));
        if (fg == 0) red[rl * 4 + wc] = m;
    }
    __syncthreads();
    float mx[4];
#pragma unroll
    for (int mi = 0; mi < 4; ++mi) {
        const int rl = base_rloc + mi * 16;
        mx[mi] = fmaxf(fmaxf(red[rl * 4 + 0], red[rl * 4 + 1]),
                       fmaxf(red[rl * 4 + 2], red[rl * 4 + 3]));
    }
    __syncthreads();

#pragma unroll
    for (int mi = 0; mi < 4; ++mi) {
        const int rl = base_rloc + mi * 16;
        float s = 0.f;
#pragma unroll
        for (int ni = 0; ni < NI; ++ni)
#pragma unroll
            for (int r = 0; r < 4; ++r) {
                const float e = __expf(acc[mi][ni][r] - mx[mi]);
                acc[mi][ni][r] = e;
                s += e;
            }
        s += __shfl_xor(s, 16);
        s += __shfl_xor(s, 32);
        if (fg == 0) red[rl * 4 + wc] = s;
    }
    __syncthreads();

#pragma unroll
    for (int mi = 0; mi < 4; ++mi) {
        const int rl = base_rloc + mi * 16;
        const float inv = 1.0f / (red[rl * 4 + 0] + red[rl * 4 + 1] +
                                  red[rl * 4 + 2] + red[rl * 4 + 3]);
        const int grow = qb * 128 + rl;
#pragma unroll
        for (int ni = 0; ni < NI; ++ni) {
            bf16x4 o;
#pragma unroll
            for (int r = 0; r < 4; ++r) o[r] = (bf16_t)(acc[mi][ni][r] * inv);
            *(bf16x4*)&Pseg[(size_t)grow * 256 + wc * Nw + ni * 16 + fg * 4] = o;
        }
    }
}

// ---------- merged: fused QK^T+softmax (blocks 0..63) + V transpose (rest) ----------
__global__ __launch_bounds__(512)
void qk_sm_tr_kernel(const bf16_t* __restrict__ qkv, bf16_t* __restrict__ P,
                     bf16_t* __restrict__ Vt)
{
    __shared__ __align__(16) char smem[26624];
    const int bid = blockIdx.x;
    const int tid = threadIdx.x;

    if (bid < 64) {
        const int seg = bid >> 1, qb = bid & 1;
        const bf16_t* Ab = qkv + (size_t)seg * 786432 + (size_t)qb * 128 * 3072;
        const bf16_t* Bb = qkv + (size_t)seg * 786432 + 1024;
        bf16_t* Pseg = P + (size_t)seg * 65536;
        if (qb) qk_block<4>(Ab, Bb, Pseg, 1, smem, tid);
        else    qk_block<2>(Ab, Bb, Pseg, 0, smem, tid);
    } else {
        const int id2 = bid - 64;
        const int seg = id2 >> 6;
        const int rem = id2 & 63;
        const int eb = rem >> 2, kb = rem & 3;
        bf16_t* tile = (bf16_t*)smem;   // [64][65]
        const int rr = tid >> 3, cs = (tid & 7) * 8;
        const bf16_t* src = qkv + ((size_t)seg * 256 + kb * 64 + rr) * 3072
                                + 2048 + eb * 64 + cs;
        bf16x8 v = *(const bf16x8*)src;
#pragma unroll
        for (int i = 0; i < 8; ++i) tile[rr * 65 + cs + i] = v[i];
        __syncthreads();
        bf16x8 o;
#pragma unroll
        for (int i = 0; i < 8; ++i) o[i] = tile[(cs + i) * 65 + rr];
        *(bf16x8*)&Vt[(size_t)seg * 262144 + (size_t)(eb * 64 + rr) * 256 + kb * 64 + cs] = o;
    }
}

// ---------- LayerNorm (in place, bf16x8, 2 rows per block) ----------
__global__ __launch_bounds__(256)
void ln_kernel(bf16_t* __restrict__ qkv,
               const float* __restrict__ gamma, const float* __restrict__ beta)
{
    const int t = threadIdx.x;
    const int r = t >> 7;
    const int row = blockIdx.x * 2 + r;
    const int which = blockIdx.y;
    bf16_t* p = qkv + (size_t)row * 3072 + which * 1024;
    const int li = t & 127;
    const int c0 = li * 8;

    bf16x8 v = *(const bf16x8*)&p[c0];
    float f[8];
    float s = 0.f, ss = 0.f;
#pragma unroll
    for (int i = 0; i < 8; ++i) { f[i] = (float)v[i]; s += f[i]; ss += f[i] * f[i]; }
#pragma unroll
    for (int o = 32; o; o >>= 1) { s += __shfl_xor(s, o); ss += __shfl_xor(ss, o); }

    __shared__ float rs_[4], rss_[4];
    const int wave = t >> 6, lane = t & 63;
    if (lane == 0) { rs_[wave] = s; rss_[wave] = ss; }
    __syncthreads();
    s  = rs_[2 * r] + rs_[2 * r + 1];
    ss = rss_[2 * r] + rss_[2 * r + 1];

    const float mu   = s * (1.f / 1024.f);
    const float var  = ss * (1.f / 1024.f) - mu * mu;
    const float rstd = rsqrtf(var + 1e-5f);

    bf16x8 o;
#pragma unroll
    for (int i = 0; i < 8; ++i)
        o[i] = (bf16_t)((f[i] - mu) * rstd * gamma[c0 + i] + beta[c0 + i]);
    *(bf16x8*)&p[c0] = o;
}

// ---------- launch ----------

extern "C" void kernel_launch(void* const* d_in, const int* in_sizes, int n_in,
                              void* d_out, int out_size, void* d_ws, size_t ws_size,
                              hipStream_t stream)
{
    const float* x     = (const float*)d_in[0];
    const float* Wq    = (const float*)d_in[1];
    const float* Wk    = (const float*)d_in[2];
    const float* Wv    = (const float*)d_in[3];
    const float* Wo    = (const float*)d_in[4];
    const float* gamma = (const float*)d_in[5];
    const float* beta  = (const float*)d_in[6];
    float* out = (float*)d_out;

    char* ws = (char*)d_ws;
    bf16_t* Xe   = (bf16_t*)(ws);                  // 8192x1024 bf16   (16 MB)
    bf16_t* Wqkv = (bf16_t*)(ws + (16u  << 20));   // 3072x1024 bf16   ( 6 MB)
    bf16_t* Wob  = (bf16_t*)(ws + (22u  << 20));   // 1024x1024 bf16   ( 2 MB)
    bf16_t* QKV  = (bf16_t*)(ws + (24u  << 20));   // 8192x3072 bf16   (48 MB)
    bf16_t* P    = (bf16_t*)(ws + (80u  << 20));   // 32x256x256 bf16  ( 4 MB)
    bf16_t* Vt   = (bf16_t*)(ws + (84u  << 20));   // 32x1024x256 bf16 (16 MB)
    bf16_t* Y    = (bf16_t*)(ws + (100u << 20));   // 8192x1024 bf16   (16 MB)

    // prep: weight casts + dilated gather (one launch)
    prep_kernel<<<12288, 256, 0, stream>>>(Wq, Wk, Wv, Wo, x, Wqkv, Wob, Xe);

    // QKV projection: 768 blocks (24 j x 32 bm) = 3 blocks/CU co-resident
    gemm_mt<0, 1><<<dim3(24, 32), 512, 0, stream>>>(
        Xe, Wqkv, QKV, 1024, 1024, 3072);

    // LayerNorm q,k,v in place
    ln_kernel<<<dim3(4096, 3), 256, 0, stream>>>(QKV, gamma, beta);

    // fused: S = QK^T -> causal softmax -> P (direct), plus V transpose
    qk_sm_tr_kernel<<<64 + 2048, 512, 0, stream>>>(QKV, P, Vt);

    // Y = P V per segment (tri: bm==0 blocks only need K=128)
    gemm_nt<0><<<dim3(8, 2, 32), 256, 0, stream>>>(
        P, Vt, Y, 256, 256, 256, 1024,
        65536L, 262144L, 262144L, 1);

    // out = Y Wo^T scattered to even rows of d_out, odd rows zeroed
    gemm_mt<2, 1><<<dim3(8, 32), 512, 0, stream>>>(
        Y, Wob, out, 1024, 1024, 1024);
}

// Round 13
// 175.892 us; speedup vs baseline: 1.0174x; 1.0046x over previous
//
#include <hip/hip_runtime.h>
#include <stdint.h>

typedef __bf16 bf16_t;
typedef __bf16 bf16x8 __attribute__((ext_vector_type(8)));
typedef __bf16 bf16x4 __attribute__((ext_vector_type(4)));
typedef float  f32x4  __attribute__((ext_vector_type(4)));

// ---------- helpers ----------

__device__ __forceinline__ void gload16(const void* g, void* lds)
{
    __builtin_amdgcn_global_load_lds(
        (__attribute__((address_space(1))) void*)(void*)g,
        (__attribute__((address_space(3))) void*)lds,
        16, 0, 0);
}

// operands swapped at call sites (mfma(b,a,acc)) -> lane holds 4 CONSECUTIVE
// COLUMNS: C[row = lane&15 (A-frag row)][col = (lane>>4)*4 + r]
__device__ __forceinline__ f32x4 mfma16(bf16x8 a, bf16x8 b, f32x4 c)
{
    return __builtin_amdgcn_mfma_f32_16x16x32_bf16(a, b, c, 0, 0, 0);
}

#define SBAR()   asm volatile("s_barrier" ::: "memory")
#define LGKM0()  asm volatile("s_waitcnt lgkmcnt(0)" ::: "memory")
#define VMCNT(N) asm volatile("s_waitcnt vmcnt(" #N ")" ::: "memory")

// ---------- prep: fused weight casts + dilated gather ----------

__global__ __launch_bounds__(256)
void prep_kernel(const float* __restrict__ Wq, const float* __restrict__ Wk,
                 const float* __restrict__ Wv, const float* __restrict__ Wo,
                 const float* __restrict__ x,
                 bf16_t* __restrict__ Wqkv, bf16_t* __restrict__ Wob,
                 bf16_t* __restrict__ Xe)
{
    const int bid = blockIdx.x;
    const int t = threadIdx.x;
    if (bid < 4096) {
        const int which = bid >> 10;
        const int blk = bid & 1023;
        const float* src = which == 0 ? Wq : which == 1 ? Wk : which == 2 ? Wv : Wo;
        bf16_t* dst = which == 3 ? Wob : Wqkv + (size_t)which * 1048576;
        const size_t i = ((size_t)blk * 256 + t) * 4;
        float4 f = *(const float4*)&src[i];
        bf16x4 o;
        o[0] = (bf16_t)f.x; o[1] = (bf16_t)f.y; o[2] = (bf16_t)f.z; o[3] = (bf16_t)f.w;
        *(bf16x4*)&dst[i] = o;
    } else {
        const int m = bid - 4096;
        const int b = m >> 11, g = (m >> 8) & 7, j = m & 255;
        const float* src = x + ((size_t)b * 4096 + g * 512 + 2 * j) * 1024;
        bf16_t* dst = Xe + (size_t)m * 1024;
        float4 f = *(const float4*)&src[t * 4];
        bf16x4 o;
        o[0] = (bf16_t)f.x; o[1] = (bf16_t)f.y; o[2] = (bf16_t)f.z; o[3] = (bf16_t)f.w;
        *(bf16x4*)&dst[t * 4] = o;
    }
}

// ---------- 256x128 GEMM, BK=32, LDS 48KB, up to 3 blocks/CU (r10-proven) ----------
template<int EPI, int NSUB>
__global__ __launch_bounds__(512, 4)
void gemm_mt(const bf16_t* __restrict__ A, const bf16_t* __restrict__ B,
             void* __restrict__ Cv, int lda, int ldb, int ldc)
{
    __shared__ __align__(16) char lds[49152];

    const int tid = threadIdx.x;
    const int w = tid >> 6, lane = tid & 63;
    const int wr = w >> 2, wc = w & 3;
    const int fr = lane & 15, fg = lane >> 4;

    const int gx = gridDim.x;
    const int lin = blockIdx.y * gx + blockIdx.x;
    const int cpx = (gx * gridDim.y) >> 3;
    const int L = (lin & 7) * cpx + (lin >> 3);
    const int bm = L / gx;
    const int j = L - bm * gx;
    const int NT = NSUB * 32;

    const int s = tid ^ ((tid >> 3) & 7);
    const char* srcA  = (const char*)A + ((size_t)(bm * 256 + (s >> 2)) * lda + (s & 3) * 8) * 2;
    const char* srcB0 = (const char*)B + ((size_t)(j * NSUB * 128 + (s >> 2)) * ldb + (s & 3) * 8) * 2;
    const size_t aHalf  = (size_t)128 * lda * 2;
    const size_t bnStep = (size_t)128 * ldb * 2;
    const int ldsW = w * 1024;

#define STG_AL(T) gload16(srcA + (size_t)((T) & 31) * 64,                          \
                          lds + ((T) & 1) * 24576 + ldsW)
#define STG_AH(T) gload16(srcA + aHalf + (size_t)((T) & 31) * 64,                  \
                          lds + ((T) & 1) * 24576 + 8192 + ldsW)
#define STG_B(T)  gload16(srcB0 + (size_t)((T) >> 5) * bnStep + (size_t)((T) & 31) * 64, \
                          lds + ((T) & 1) * 24576 + 16384 + ldsW)

    const int flip = ((fr >> 1) & 7) << 4;
    const int aoff = wr * 8192 + fr * 64 + fg * 16;
    const int boff = 16384 + wc * 2048 + fr * 64 + fg * 16;

    bf16x8 a[4], b[2];
    f32x4 acc[8][2] = {};

#define LDA(PH, CB) do {                                                        \
    _Pragma("unroll") for (int mi = 0; mi < 4; ++mi)                            \
        a[mi] = *(const bf16x8*)(lds + (CB) +                                   \
            ((aoff + (PH) * 4096 + mi * 1024) ^ flip));                         \
} while (0)

#define LDB(CB) do {                                                            \
    _Pragma("unroll") for (int ni = 0; ni < 2; ++ni)                            \
        b[ni] = *(const bf16x8*)(lds + (CB) +                                   \
            ((boff + ni * 1024) ^ flip));                                       \
} while (0)

#define MF(PH) do {                                                             \
    _Pragma("unroll") for (int mi = 0; mi < 4; ++mi)                            \
    _Pragma("unroll") for (int ni = 0; ni < 2; ++ni)                            \
        acc[(PH) * 4 + mi][ni] =                                                \
            mfma16(b[ni], a[mi], acc[(PH) * 4 + mi][ni]);                       \
} while (0)

    const int r0 = bm * 256 + wr * 128 + fr;
    const int c0w = wc * 32 + fg * 4;

#define DO_EPI(SUB) do {                                                                  \
    const int _c0 = (j * NSUB + (SUB)) * 128 + c0w;                                       \
    if constexpr (EPI == 0) {                                                             \
        bf16_t* C = (bf16_t*)Cv;                                                          \
        _Pragma("unroll") for (int mig = 0; mig < 8; ++mig)                               \
        _Pragma("unroll") for (int ni = 0; ni < 2; ++ni) {                                \
            const int row = r0 + (mig >> 2) * 64 + (mig & 3) * 16;                        \
            bf16x4 o;                                                                     \
            _Pragma("unroll") for (int r = 0; r < 4; ++r) o[r] = (bf16_t)acc[mig][ni][r]; \
            *(bf16x4*)&C[(size_t)row * ldc + _c0 + ni * 16] = o;                          \
        }                                                                                 \
    } else {                                                                              \
        float* C = (float*)Cv;                                                            \
        const f32x4 z4 = {0.f, 0.f, 0.f, 0.f};                                            \
        _Pragma("unroll") for (int mig = 0; mig < 8; ++mig)                               \
        _Pragma("unroll") for (int ni = 0; ni < 2; ++ni) {                                \
            const int m  = r0 + (mig >> 2) * 64 + (mig & 3) * 16;                         \
            const int gr = ((m >> 11) << 12) | (((m >> 8) & 7) << 9) | ((m & 255) << 1);  \
            *(f32x4*)&C[(size_t)gr * 1024 + _c0 + ni * 16]       = acc[mig][ni];          \
            *(f32x4*)&C[(size_t)(gr + 1) * 1024 + _c0 + ni * 16] = z4;                    \
        }                                                                                 \
    }                                                                                     \
    _Pragma("unroll") for (int mig = 0; mig < 8; ++mig)                                   \
    _Pragma("unroll") for (int ni = 0; ni < 2; ++ni)                                      \
        acc[mig][ni] = (f32x4){0.f, 0.f, 0.f, 0.f};                                       \
} while (0)

    STG_AL(0); STG_AH(0); STG_B(0);
    STG_B(1);
    VMCNT(1);
    SBAR();

    for (int t = 0; t <= NT - 3; ++t) {
        const int cb = (t & 1) * 24576;
        LDA(0, cb); LDB(cb);
        STG_AL(t + 1); STG_AH(t + 1);
        SBAR(); LGKM0();
        __builtin_amdgcn_s_setprio(1); MF(0); __builtin_amdgcn_s_setprio(0);
        VMCNT(3);
        SBAR();
        LDA(1, cb);
        STG_B(t + 2);
        SBAR(); LGKM0();
        __builtin_amdgcn_s_setprio(1); MF(1); __builtin_amdgcn_s_setprio(0);
        VMCNT(1);
        if (NSUB > 1 && (t & 31) == 31) DO_EPI(t >> 5);
        SBAR();
    }

    {
        const int cb = ((NT - 2) & 1) * 24576;
        LDA(0, cb); LDB(cb);
        STG_AL(NT - 1); STG_AH(NT - 1);
        SBAR(); LGKM0();
        MF(0);
        VMCNT(3);
        SBAR();
        LDA(1, cb);
        SBAR(); LGKM0();
        MF(1);
        VMCNT(0);
        SBAR();
    }
    {
        const int cb = ((NT - 1) & 1) * 24576;
        LDA(0, cb); LDB(cb);
        LGKM0();
        MF(0);
        LDA(1, cb);
        LGKM0();
        MF(1);
    }
    DO_EPI(NSUB - 1);

#undef STG_AL
#undef STG_AH
#undef STG_B
#undef LDA
#undef LDB
#undef MF
#undef DO_EPI
}

// ---------- GEMM: C[M,N] = A[M,K] * B[N,K]^T (128x128 tile, swizzled m97) ----------
// flags bit0 = triangular-A K-skip (bm==0 -> K/2). Used for PV.
template<int EPI>   // 0 = store bf16, 1 = store f32
__global__ __launch_bounds__(256)
void gemm_nt(const bf16_t* __restrict__ A, const bf16_t* __restrict__ B,
             void* __restrict__ Cv,
             int K, int lda, int ldb, int ldc,
             long sA, long sB, long sC, int flags)
{
    __shared__ __align__(16) bf16_t Asm[128 * 32];
    __shared__ __align__(16) bf16_t Bsm[128 * 32];

    const int bn = blockIdx.x, bm = blockIdx.y, bz = blockIdx.z;
    const int tid  = threadIdx.x;
    const int wave = tid >> 6;
    const int lane = tid & 63;
    const int wr = wave >> 1, wc = wave & 1;

    const bf16_t* Ab = A + (long)bz * sA;
    const bf16_t* Bb = B + (long)bz * sB;

    const int Keff = ((flags & 1) && bm == 0) ? (K >> 1) : K;

    const int sw0 = tid ^ ((tid >> 3) & 3);
    const int dd1 = tid + 256;
    const int sw1 = dd1 ^ ((dd1 >> 3) & 3);
    const bf16_t* a0 = Ab + (size_t)(bm * 128 + (sw0 >> 2)) * lda + (sw0 & 3) * 8;
    const bf16_t* a1 = Ab + (size_t)(bm * 128 + (sw1 >> 2)) * lda + (sw1 & 3) * 8;
    const bf16_t* b0 = Bb + (size_t)(bn * 128 + (sw0 >> 2)) * ldb + (sw0 & 3) * 8;
    const bf16_t* b1 = Bb + (size_t)(bn * 128 + (sw1 >> 2)) * ldb + (sw1 & 3) * 8;
    char* ldsA = (char*)Asm + wave * 1024;
    char* ldsB = (char*)Bsm + wave * 1024;

    f32x4 acc[4][4] = {};

    const int frow = lane & 15;
    const int fk   = (lane >> 4) * 8;
    const int flip = (frow & 6) << 2;

    for (int k0 = 0; k0 < Keff; k0 += 32) {
        gload16(a0, ldsA);
        gload16(a1, ldsA + 4096);
        gload16(b0, ldsB);
        gload16(b1, ldsB + 4096);
        a0 += 32; a1 += 32; b0 += 32; b1 += 32;
        __syncthreads();

        bf16x8 af[4], bfr[4];
#pragma unroll
        for (int mi = 0; mi < 4; ++mi)
            af[mi] = *(const bf16x8*)&Asm[(size_t)(((wr * 64 + mi * 16 + frow) * 32 + fk) ^ flip)];
#pragma unroll
        for (int ni = 0; ni < 4; ++ni)
            bfr[ni] = *(const bf16x8*)&Bsm[(size_t)(((wc * 64 + ni * 16 + frow) * 32 + fk) ^ flip)];
#pragma unroll
        for (int mi = 0; mi < 4; ++mi)
#pragma unroll
            for (int ni = 0; ni < 4; ++ni)
                acc[mi][ni] = mfma16(bfr[ni], af[mi], acc[mi][ni]);   // swapped
        __syncthreads();
    }

    const int row0 = bm * 128 + wr * 64 + frow;
    const int col0 = bn * 128 + wc * 64 + (lane >> 4) * 4;

    if constexpr (EPI == 0) {
        bf16_t* C = (bf16_t*)Cv + (long)bz * sC;
#pragma unroll
        for (int mi = 0; mi < 4; ++mi)
#pragma unroll
            for (int ni = 0; ni < 4; ++ni) {
                bf16x4 o;
#pragma unroll
                for (int r = 0; r < 4; ++r) o[r] = (bf16_t)acc[mi][ni][r];
                *(bf16x4*)&C[(size_t)(row0 + mi * 16) * ldc + col0 + ni * 16] = o;
            }
    } else {
        float* C = (float*)Cv + (long)bz * sC;
#pragma unroll
        for (int mi = 0; mi < 4; ++mi)
#pragma unroll
            for (int ni = 0; ni < 4; ++ni)
                *(f32x4*)&C[(size_t)(row0 + mi * 16) * ldc + col0 + ni * 16] = acc[mi][ni];
    }
}

// ---------- fused QK^T + causal softmax (device body) ----------
template<int NI>
__device__ __forceinline__ void qk_block(
    const bf16_t* __restrict__ Ab, const bf16_t* __restrict__ Bb,
    bf16_t* __restrict__ Pseg, int qb, char* smem, int tid)
{
    bf16_t* Asm = (bf16_t*)smem;                 // [128][32]
    bf16_t* Bsm = (bf16_t*)(smem + 8192);        // [NI*64][32]
    float*  red = (float*)(smem + 24576);        // [128][4]

    const int w = tid >> 6, lane = tid & 63;
    const int wr = w >> 2, wc = w & 3;
    const int frow = lane & 15, fg = lane >> 4;

    const int g0 = tid, g1 = tid + 512;
    const int s0 = g0 ^ ((g0 >> 3) & 3);
    const int s1 = g1 ^ ((g1 >> 3) & 3);
    const bf16_t* a0 = Ab + (size_t)(s0 >> 2) * 3072 + (s0 & 3) * 8;
    const bf16_t* b0 = Bb + (size_t)(s0 >> 2) * 3072 + (s0 & 3) * 8;
    const bf16_t* b1 = Bb + (size_t)(s1 >> 2) * 3072 + (s1 & 3) * 8;
    char* ldsA = smem + w * 1024;
    char* ldsB = smem + 8192 + w * 1024;

    f32x4 acc[4][NI] = {};
    const int fk = fg * 8;
    const int flip = (frow & 6) << 2;
    const int Nw = NI * 16;

    for (int k0 = 0; k0 < 1024; k0 += 32) {
        gload16(a0, ldsA);
        gload16(b0, ldsB);
        if (NI == 4) gload16(b1, ldsB + 8192);
        a0 += 32; b0 += 32; b1 += 32;
        __syncthreads();

        bf16x8 af[4], bf_[NI];
#pragma unroll
        for (int mi = 0; mi < 4; ++mi)
            af[mi] = *(const bf16x8*)&Asm[((wr * 64 + mi * 16 + frow) * 32 + fk) ^ flip];
#pragma unroll
        for (int ni = 0; ni < NI; ++ni)
            bf_[ni] = *(const bf16x8*)&Bsm[((wc * Nw + ni * 16 + frow) * 32 + fk) ^ flip];
#pragma unroll
        for (int mi = 0; mi < 4; ++mi)
#pragma unroll
            for (int ni = 0; ni < NI; ++ni)
                acc[mi][ni] = mfma16(bf_[ni], af[mi], acc[mi][ni]);   // swapped
        __syncthreads();
    }

    // ---- softmax epilogue ----
    const int base_rloc = wr * 64 + frow;
    const float scale = 1.0f / 32.0f;

#pragma unroll
    for (int mi = 0; mi < 4; ++mi) {
        const int rl = base_rloc + mi * 16;
        const int grow = qb * 128 + rl;
        float m = -3.0e38f;
#pragma unroll
        for (int ni = 0; ni < NI; ++ni)
#pragma unroll
            for (int r = 0; r < 4; ++r) {
                const int col = wc * Nw + ni * 16 + fg * 4 + r;
                float v = acc[mi][ni][r] * scale;
                if (col > grow) v = -3.0e38f;
                acc[mi][ni][r] = v;
                m = fmaxf(m, v);
            }
        m = fmaxf(m, __shfl_xor(m, 16));
        m = fmaxf(m, __shfl_xor(m, 32));
        if (fg == 0) red[rl * 4 + wc] = m;
    }
    __syncthreads();
    float mx[4];
#pragma unroll
    for (int mi = 0; mi < 4; ++mi) {
        const int rl = base_rloc + mi * 16;
        mx[mi] = fmaxf(fmaxf(red[rl * 4 + 0], red[rl * 4 + 1]),
                       fmaxf(red[rl * 4 + 2], red[rl * 4 + 3]));
    }
    __syncthreads();

#pragma unroll
    for (int mi = 0; mi < 4; ++mi) {
        const int rl = base_rloc + mi * 16;
        float s = 0.f;
#pragma unroll
        for (int ni = 0; ni < NI; ++ni)
#pragma unroll
            for (int r = 0; r < 4; ++r) {
                const float e = __expf(acc[mi][ni][r] - mx[mi]);
                acc[mi][ni][r] = e;
                s += e;
            }
        s += __shfl_xor(s, 16);
        s += __shfl_xor(s, 32);
        if (fg == 0) red[rl * 4 + wc] = s;
    }
    __syncthreads();

#pragma unroll
    for (int mi = 0; mi < 4; ++mi) {
        const int rl = base_rloc + mi * 16;
        const float inv = 1.0f / (red[rl * 4 + 0] + red[rl * 4 + 1] +
                                  red[rl * 4 + 2] + red[rl * 4 + 3]);
        const int grow = qb * 128 + rl;
#pragma unroll
        for (int ni = 0; ni < NI; ++ni) {
            bf16x4 o;
#pragma unroll
            for (int r = 0; r < 4; ++r) o[r] = (bf16_t)(acc[mi][ni][r] * inv);
            *(bf16x4*)&Pseg[(size_t)grow * 256 + wc * Nw + ni * 16 + fg * 4] = o;
        }
    }
}

// ---------- merged: fused QK^T+softmax (blocks 0..63) + LN'd V transpose (rest) ----------
__global__ __launch_bounds__(512)
void qk_sm_tr_kernel(const bf16_t* __restrict__ qkv, bf16_t* __restrict__ P,
                     bf16_t* __restrict__ Vt, const float* __restrict__ Vstats,
                     const float* __restrict__ gamma, const float* __restrict__ beta)
{
    __shared__ __align__(16) char smem[26624];
    const int bid = blockIdx.x;
    const int tid = threadIdx.x;

    if (bid < 64) {
        const int seg = bid >> 1, qb = bid & 1;
        const bf16_t* Ab = qkv + (size_t)seg * 786432 + (size_t)qb * 128 * 3072;
        const bf16_t* Bb = qkv + (size_t)seg * 786432 + 1024;
        bf16_t* Pseg = P + (size_t)seg * 65536;
        if (qb) qk_block<4>(Ab, Bb, Pseg, 1, smem, tid);
        else    qk_block<2>(Ab, Bb, Pseg, 0, smem, tid);
    } else {
        const int id2 = bid - 64;
        const int seg = id2 >> 6;
        const int rem = id2 & 63;
        const int eb = rem >> 2, kb = rem & 3;
        bf16_t* tile = (bf16_t*)smem;   // [64][65]
        const int rr = tid >> 3, cs = (tid & 7) * 8;
        const int row = seg * 256 + kb * 64 + rr;
        const bf16_t* src = qkv + (size_t)row * 3072 + 2048 + eb * 64 + cs;
        bf16x8 v = *(const bf16x8*)src;
        const float mu   = Vstats[row * 2];
        const float rstd = Vstats[row * 2 + 1];
#pragma unroll
        for (int i = 0; i < 8; ++i) {
            const int e = eb * 64 + cs + i;
            const float f = ((float)v[i] - mu) * rstd * gamma[e] + beta[e];
            tile[rr * 65 + cs + i] = (bf16_t)f;
        }
        __syncthreads();
        bf16x8 o;
#pragma unroll
        for (int i = 0; i < 8; ++i) o[i] = tile[(cs + i) * 65 + rr];
        *(bf16x8*)&Vt[(size_t)seg * 262144 + (size_t)(eb * 64 + rr) * 256 + kb * 64 + cs] = o;
    }
}

// ---------- LayerNorm: q,k in place; v -> stats only ----------
__global__ __launch_bounds__(256)
void ln_kernel(bf16_t* __restrict__ qkv, float* __restrict__ Vstats,
               const float* __restrict__ gamma, const float* __restrict__ beta)
{
    const int t = threadIdx.x;
    const int r = t >> 7;
    const int row = blockIdx.x * 2 + r;
    const int which = blockIdx.y;    // 0=q 1=k 2=v(stats only)
    bf16_t* p = qkv + (size_t)row * 3072 + which * 1024;
    const int li = t & 127;
    const int c0 = li * 8;

    bf16x8 v = *(const bf16x8*)&p[c0];
    float f[8];
    float s = 0.f, ss = 0.f;
#pragma unroll
    for (int i = 0; i < 8; ++i) { f[i] = (float)v[i]; s += f[i]; ss += f[i] * f[i]; }
#pragma unroll
    for (int o = 32; o; o >>= 1) { s += __shfl_xor(s, o); ss += __shfl_xor(ss, o); }

    __shared__ float rs_[4], rss_[4];
    const int wave = t >> 6, lane = t & 63;
    if (lane == 0) { rs_[wave] = s; rss_[wave] = ss; }
    __syncthreads();
    s  = rs_[2 * r] + rs_[2 * r + 1];
    ss = rss_[2 * r] + rss_[2 * r + 1];

    const float mu   = s * (1.f / 1024.f);
    const float var  = ss * (1.f / 1024.f) - mu * mu;
    const float rstd = rsqrtf(var + 1e-5f);

    if (which == 2) {
        if (li == 0) {
            Vstats[row * 2]     = mu;
            Vstats[row * 2 + 1] = rstd;
        }
        return;
    }

    bf16x8 o;
#pragma unroll
    for (int i = 0; i < 8; ++i)
        o[i] = (bf16_t)((f[i] - mu) * rstd * gamma[c0 + i] + beta[c0 + i]);
    *(bf16x8*)&p[c0] = o;
}

// ---------- launch ----------

extern "C" void kernel_launch(void* const* d_in, const int* in_sizes, int n_in,
                              void* d_out, int out_size, void* d_ws, size_t ws_size,
                              hipStream_t stream)
{
    const float* x     = (const float*)d_in[0];
    const float* Wq    = (const float*)d_in[1];
    const float* Wk    = (const float*)d_in[2];
    const float* Wv    = (const float*)d_in[3];
    const float* Wo    = (const float*)d_in[4];
    const float* gamma = (const float*)d_in[5];
    const float* beta  = (const float*)d_in[6];
    float* out = (float*)d_out;

    char* ws = (char*)d_ws;
    bf16_t* Xe   = (bf16_t*)(ws);                  // 8192x1024 bf16   (16 MB)
    bf16_t* Wqkv = (bf16_t*)(ws + (16u  << 20));   // 3072x1024 bf16   ( 6 MB)
    bf16_t* Wob  = (bf16_t*)(ws + (22u  << 20));   // 1024x1024 bf16   ( 2 MB)
    bf16_t* QKV  = (bf16_t*)(ws + (24u  << 20));   // 8192x3072 bf16   (48 MB)
    float*  Vst  = (float*) (ws + (76u  << 20));   // 8192x2 f32       (64 KB)
    bf16_t* P    = (bf16_t*)(ws + (80u  << 20));   // 32x256x256 bf16  ( 4 MB)
    bf16_t* Vt   = (bf16_t*)(ws + (84u  << 20));   // 32x1024x256 bf16 (16 MB)
    bf16_t* Y    = (bf16_t*)(ws + (100u << 20));   // 8192x1024 bf16   (16 MB)

    // prep: weight casts + dilated gather (one launch)
    prep_kernel<<<12288, 256, 0, stream>>>(Wq, Wk, Wv, Wo, x, Wqkv, Wob, Xe);

    // QKV projection: 768 blocks = 3/CU co-resident (r10-proven: 65.7us)
    gemm_mt<0, 1><<<dim3(24, 32), 512, 0, stream>>>(
        Xe, Wqkv, QKV, 1024, 1024, 3072);

    // LayerNorm q,k in place; v -> stats
    ln_kernel<<<dim3(4096, 3), 256, 0, stream>>>(QKV, Vst, gamma, beta);

    // fused: QK^T -> causal softmax -> P; LN'd V transpose
    qk_sm_tr_kernel<<<64 + 2048, 512, 0, stream>>>(QKV, P, Vt, Vst, gamma, beta);

    // Y = P V per segment (tri: bm==0 blocks only need K=128)
    gemm_nt<0><<<dim3(8, 2, 32), 256, 0, stream>>>(
        P, Vt, Y, 256, 256, 256, 1024,
        65536L, 262144L, 262144L, 1);

    // out = Y Wo^T scattered to d_out: r10-proven gemm_mt<2,1> (replay-validated)
    gemm_mt<2, 1><<<dim3(8, 32), 512, 0, stream>>>(
        Y, Wob, out, 1024, 1024, 1024);
}